// Round 1
// baseline (1340.072 us; speedup 1.0000x reference)
//
#include <hip/hip_runtime.h>
#include <math.h>

#define B_ 16
#define S_ 256
#define D_ 1024
#define HP_ 16
#define DK_ 64
#define HC_ 8
#define SK_ 32
#define EPS_ 1e-6f

// ---------------- K1: LayerNorm over channels (per row of D=1024) ----------------
__global__ __launch_bounds__(256) void k1_ln_p(
    const float* __restrict__ x, const float* __restrict__ a_p,
    const float* __restrict__ b_p, float* __restrict__ out)
{
    const int row = blockIdx.x;                  // b*S + s
    const float4* xr = (const float4*)(x + (size_t)row * D_);
    float4* orow = (float4*)(out + (size_t)row * D_);
    const int tid = threadIdx.x;
    float4 v = xr[tid];
    float s  = v.x + v.y + v.z + v.w;
    float sq = v.x*v.x + v.y*v.y + v.z*v.z + v.w*v.w;
    #pragma unroll
    for (int off = 32; off > 0; off >>= 1) {
        s  += __shfl_down(s, off);
        sq += __shfl_down(sq, off);
    }
    __shared__ float red[8];
    const int wid = tid >> 6, lane = tid & 63;
    if (lane == 0) { red[wid] = s; red[4 + wid] = sq; }
    __syncthreads();
    if (tid == 0) {
        float S0 = red[0] + red[1] + red[2] + red[3];
        float Q0 = red[4] + red[5] + red[6] + red[7];
        float mean = S0 / (float)D_;
        float var  = fmaxf((Q0 - (float)D_ * mean * mean) / (float)(D_ - 1), 0.0f);
        red[0] = mean;
        red[1] = 1.0f / (sqrtf(var) + EPS_);     // torch std(): unbiased; eps on std
    }
    __syncthreads();
    const float mean = red[0], inv = red[1];
    float4 a = ((const float4*)a_p)[tid];
    float4 b = ((const float4*)b_p)[tid];
    float4 o;
    o.x = a.x * (v.x - mean) * inv + b.x;
    o.y = a.y * (v.y - mean) * inv + b.y;
    o.z = a.z * (v.z - mean) * inv + b.z;
    o.w = a.w * (v.w - mean) * inv + b.w;
    orow[tid] = o;
}

// ---------------- Generic f32 matmul C[m,n] = sum_k A[m,k]*B[k,n] + bias[n] ------
// 128x128 tile, BK=16, 256 threads, 8x8 per thread. All dims divide tiles.
__global__ __launch_bounds__(256) void mm_bias(
    const float* __restrict__ A, const float* __restrict__ Bm,
    const float* __restrict__ bias, float* __restrict__ C,
    int M, int N, int K, long sB, long sBias, long sC)
{
    const int n = blockIdx.z;
    Bm   += (size_t)n * sB;
    bias += (size_t)n * sBias;
    C    += (size_t)n * sC;
    const int m0 = blockIdx.y * 128, n0 = blockIdx.x * 128;
    __shared__ float As[16][132];   // transposed: As[k][m]
    __shared__ float Bs[16][132];
    const int tid = threadIdx.x;
    const int tx = tid & 15, ty = tid >> 4;
    const int arow = tid >> 2, acol = (tid & 3) * 4;
    const int brow = tid >> 5, bcol = (tid & 31) * 4;
    float acc[8][8];
    {
        float4 bi0 = *(const float4*)&bias[n0 + tx*8];
        float4 bi1 = *(const float4*)&bias[n0 + tx*8 + 4];
        #pragma unroll
        for (int i = 0; i < 8; i++) {
            acc[i][0]=bi0.x; acc[i][1]=bi0.y; acc[i][2]=bi0.z; acc[i][3]=bi0.w;
            acc[i][4]=bi1.x; acc[i][5]=bi1.y; acc[i][6]=bi1.z; acc[i][7]=bi1.w;
        }
    }
    for (int k0 = 0; k0 < K; k0 += 16) {
        float4 a0 = *(const float4*)&A[(size_t)(m0 + arow     ) * K + k0 + acol];
        float4 a1 = *(const float4*)&A[(size_t)(m0 + arow + 64) * K + k0 + acol];
        float4 b0 = *(const float4*)&Bm[(size_t)(k0 + brow    ) * N + n0 + bcol];
        float4 b1 = *(const float4*)&Bm[(size_t)(k0 + brow + 8) * N + n0 + bcol];
        __syncthreads();
        As[acol+0][arow] = a0.x; As[acol+1][arow] = a0.y;
        As[acol+2][arow] = a0.z; As[acol+3][arow] = a0.w;
        As[acol+0][arow+64] = a1.x; As[acol+1][arow+64] = a1.y;
        As[acol+2][arow+64] = a1.z; As[acol+3][arow+64] = a1.w;
        *(float4*)&Bs[brow][bcol]   = b0;
        *(float4*)&Bs[brow+8][bcol] = b1;
        __syncthreads();
        #pragma unroll
        for (int kk = 0; kk < 16; kk++) {
            float4 af0 = *(const float4*)&As[kk][ty*8];
            float4 af1 = *(const float4*)&As[kk][ty*8+4];
            float4 bf0 = *(const float4*)&Bs[kk][tx*8];
            float4 bf1 = *(const float4*)&Bs[kk][tx*8+4];
            float ar[8] = {af0.x,af0.y,af0.z,af0.w,af1.x,af1.y,af1.z,af1.w};
            float br[8] = {bf0.x,bf0.y,bf0.z,bf0.w,bf1.x,bf1.y,bf1.z,bf1.w};
            #pragma unroll
            for (int i = 0; i < 8; i++)
                #pragma unroll
                for (int j = 0; j < 8; j++)
                    acc[i][j] = fmaf(ar[i], br[j], acc[i][j]);
        }
    }
    #pragma unroll
    for (int i = 0; i < 8; i++) {
        float4 o0 = {acc[i][0],acc[i][1],acc[i][2],acc[i][3]};
        float4 o1 = {acc[i][4],acc[i][5],acc[i][6],acc[i][7]};
        float* cr = &C[(size_t)(m0 + ty*8 + i) * N + n0 + tx*8];
        *(float4*)cr     = o0;
        *(float4*)(cr+4) = o1;
    }
}

// ---------------- K3: positional attention, one block per (b,h), thread=query ----
__global__ __launch_bounds__(256) void k3_attn_p(
    const float* __restrict__ q, const float* __restrict__ k,
    const float* __restrict__ v, float* __restrict__ out)
{
    const int b = blockIdx.x >> 4, h = blockIdx.x & 15;
    const size_t base = (size_t)b * S_ * D_ + (size_t)h * DK_;
    __shared__ float Ks[64][68];
    __shared__ float Vs[64][68];
    const int tid = threadIdx.x;
    float4 qf[16];
    {
        const float4* qr = (const float4*)(q + base + (size_t)tid * D_);
        #pragma unroll
        for (int u = 0; u < 16; u++) qf[u] = qr[u];
    }
    float4 o[16];
    #pragma unroll
    for (int u = 0; u < 16; u++) o[u] = make_float4(0.f,0.f,0.f,0.f);
    float l = 0.0f;
    const int lr = tid >> 4, lc = (tid & 15) * 4;
    for (int kt = 0; kt < 4; kt++) {
        __syncthreads();
        #pragma unroll
        for (int u = 0; u < 4; u++) {
            const int row = lr + u * 16;
            const size_t g = base + (size_t)(kt*64 + row) * D_ + lc;
            *(float4*)&Ks[row][lc] = *(const float4*)&k[g];
            *(float4*)&Vs[row][lc] = *(const float4*)&v[g];
        }
        __syncthreads();
        for (int sk = 0; sk < 64; sk++) {
            float s0=0.f, s1=0.f, s2=0.f, s3=0.f;
            #pragma unroll
            for (int u = 0; u < 16; u++) {
                float4 kf = *(const float4*)&Ks[sk][u*4];
                s0 = fmaf(qf[u].x, kf.x, s0);
                s1 = fmaf(qf[u].y, kf.y, s1);
                s2 = fmaf(qf[u].z, kf.z, s2);
                s3 = fmaf(qf[u].w, kf.w, s3);
            }
            // scores bounded (|s|~O(3)): safe max-free softmax
            const float p = __expf(((s0+s1)+(s2+s3)) * 0.125f);
            l += p;
            #pragma unroll
            for (int u = 0; u < 16; u++) {
                float4 vf = *(const float4*)&Vs[sk][u*4];
                o[u].x = fmaf(p, vf.x, o[u].x);
                o[u].y = fmaf(p, vf.y, o[u].y);
                o[u].z = fmaf(p, vf.z, o[u].z);
                o[u].w = fmaf(p, vf.w, o[u].w);
            }
        }
    }
    const float invl = 1.0f / l;
    float4* orow = (float4*)(out + base + (size_t)tid * D_);
    #pragma unroll
    for (int u = 0; u < 16; u++)
        orow[u] = make_float4(o[u].x*invl, o[u].y*invl, o[u].z*invl, o[u].w*invl);
}

// ---------------- K4a: per-(b,d) stats over sequence dim ----------------
__global__ __launch_bounds__(256) void k4a_stats(
    const float* __restrict__ x, float* __restrict__ meanc, float* __restrict__ invc)
{
    const int d = blockIdx.x * 256 + threadIdx.x;   // 0..1023
    const int b = blockIdx.y;
    const float* p = x + (size_t)b * S_ * D_ + d;
    float s = 0.f, q = 0.f;
    for (int t = 0; t < S_; t++) { float vv = p[(size_t)t * D_]; s += vv; q += vv*vv; }
    const float mean = s / (float)S_;
    const float var  = fmaxf((q - (float)S_ * mean * mean) / (float)(S_ - 1), 0.0f);
    meanc[b*D_ + d] = mean;
    invc[b*D_ + d]  = 1.0f / (sqrtf(var) + EPS_);
}

// ---------------- K4b: normalize (LN over seq) + transpose to [B,D,S] ----------
__global__ __launch_bounds__(256) void k4b_ntrans(
    const float* __restrict__ x, const float* __restrict__ meanc,
    const float* __restrict__ invc, const float* __restrict__ a_c,
    const float* __restrict__ b_c, float* __restrict__ xt)
{
    const int s0 = blockIdx.x * 64, d0 = blockIdx.y * 64, b = blockIdx.z;
    __shared__ float tile[64][65];
    const int ix = threadIdx.x & 63, iy = threadIdx.x >> 6;
    const int d = d0 + ix;
    const float mean = meanc[b*D_ + d], inv = invc[b*D_ + d];
    #pragma unroll
    for (int u = 0; u < 16; u++) {
        const int srow = iy*16 + u;
        const float vv = x[((size_t)(b*S_ + s0 + srow)) * D_ + d];
        tile[srow][ix] = a_c[s0+srow] * (vv - mean) * inv + b_c[s0+srow];
    }
    __syncthreads();
    #pragma unroll
    for (int u = 0; u < 16; u++) {
        const int drow = iy*16 + u;
        xt[((size_t)(b*D_ + d0 + drow)) * S_ + s0 + ix] = tile[ix][drow];
    }
}

// ---------------- K6: channel attention, tokens = channels (D=1024), dk=32 -------
__global__ __launch_bounds__(256) void k6_attn_c(
    const float* __restrict__ qc, const float* __restrict__ kc,
    const float* __restrict__ vc, float* __restrict__ out)
{
    const int qt = blockIdx.x, h = blockIdx.y, b = blockIdx.z;
    const int tid = threadIdx.x;
    const int dtok = qt * 256 + tid;
    const size_t rowb = (size_t)b * D_;
    const size_t hoff = (size_t)h * SK_;
    __shared__ float Ks[128][36];
    __shared__ float Vs[128][36];
    float4 qf[8];
    {
        const float4* qr = (const float4*)(qc + (rowb + dtok) * S_ + hoff);
        #pragma unroll
        for (int u = 0; u < 8; u++) qf[u] = qr[u];
    }
    float4 o[8];
    #pragma unroll
    for (int u = 0; u < 8; u++) o[u] = make_float4(0.f,0.f,0.f,0.f);
    float l = 0.0f;
    const int lr = tid >> 3, lc = (tid & 7) * 4;
    for (int kt = 0; kt < 8; kt++) {
        __syncthreads();
        #pragma unroll
        for (int u = 0; u < 4; u++) {
            const int row = lr + u * 32;
            const size_t g = (rowb + kt*128 + row) * S_ + hoff + lc;
            *(float4*)&Ks[row][lc] = *(const float4*)&kc[g];
            *(float4*)&Vs[row][lc] = *(const float4*)&vc[g];
        }
        __syncthreads();
        for (int sk = 0; sk < 128; sk++) {
            float s0=0.f, s1=0.f, s2=0.f, s3=0.f;
            #pragma unroll
            for (int u = 0; u < 8; u++) {
                float4 kf = *(const float4*)&Ks[sk][u*4];
                s0 = fmaf(qf[u].x, kf.x, s0);
                s1 = fmaf(qf[u].y, kf.y, s1);
                s2 = fmaf(qf[u].z, kf.z, s2);
                s3 = fmaf(qf[u].w, kf.w, s3);
            }
            const float p = __expf(((s0+s1)+(s2+s3)) * 0.17677669529663687f); // 1/sqrt(32)
            l += p;
            #pragma unroll
            for (int u = 0; u < 8; u++) {
                float4 vf = *(const float4*)&Vs[sk][u*4];
                o[u].x = fmaf(p, vf.x, o[u].x);
                o[u].y = fmaf(p, vf.y, o[u].y);
                o[u].z = fmaf(p, vf.z, o[u].z);
                o[u].w = fmaf(p, vf.w, o[u].w);
            }
        }
    }
    const float invl = 1.0f / l;
    float4* orow = (float4*)(out + (rowb + dtok) * S_ + hoff);
    #pragma unroll
    for (int u = 0; u < 8; u++)
        orow[u] = make_float4(o[u].x*invl, o[u].y*invl, o[u].z*invl, o[u].w*invl);
}

// ---------------- K8: final transpose [B,D,S] -> [B,S,D] ----------------
__global__ __launch_bounds__(256) void k8_trans(
    const float* __restrict__ y, float* __restrict__ out)
{
    const int e0 = blockIdx.x * 64, d0 = blockIdx.y * 64, b = blockIdx.z;
    __shared__ float tile[64][65];
    const int ix = threadIdx.x & 63, iy = threadIdx.x >> 6;
    #pragma unroll
    for (int u = 0; u < 16; u++) {
        const int drow = iy*16 + u;
        tile[drow][ix] = y[((size_t)(b*D_ + d0 + drow)) * S_ + e0 + ix];
    }
    __syncthreads();
    #pragma unroll
    for (int u = 0; u < 16; u++) {
        const int erow = iy*16 + u;
        out[((size_t)(b*S_ + e0 + erow)) * D_ + d0 + ix] = tile[ix][erow];
    }
}

extern "C" void kernel_launch(void* const* d_in, const int* in_sizes, int n_in,
                              void* d_out, int out_size, void* d_ws, size_t ws_size,
                              hipStream_t stream)
{
    const float* x   = (const float*)d_in[0];
    const float* Wp  = (const float*)d_in[1];
    const float* bp  = (const float*)d_in[2];
    const float* Wc  = (const float*)d_in[3];
    const float* bc  = (const float*)d_in[4];
    const float* a_p = (const float*)d_in[5];
    const float* b_p = (const float*)d_in[6];
    const float* a_c = (const float*)d_in[7];
    const float* b_c = (const float*)d_in[8];
    float* out = (float*)d_out;
    float* ws  = (float*)d_ws;
    const size_t NE = (size_t)B_ * S_ * D_;   // 4,194,304

    float* R0 = ws;             // xp -> attn_out -> vc -> y
    float* R1 = ws + NE;        // q  -> xt -> xcatt
    float* R2 = ws + 2*NE;      // k  -> qc
    float* R3 = ws + 3*NE;      // v  -> kc
    float* meanc = ws + 4*NE;
    float* invc  = meanc + (size_t)B_*D_;

    // 1) LayerNorm over channels: x -> R0
    k1_ln_p<<<dim3(B_*S_), 256, 0, stream>>>(x, a_p, b_p, R0);
    // 2) QKV projection: R0 @ Wp[n] + bp[n] -> R1,R2,R3
    mm_bias<<<dim3(D_/128, (B_*S_)/128, 3), 256, 0, stream>>>(
        R0, Wp, bp, R1, B_*S_, D_, D_, (long)D_*D_, (long)D_, (long)NE);
    // 3) positional attention -> R0
    k3_attn_p<<<dim3(B_*HP_), 256, 0, stream>>>(R1, R2, R3, R0);
    // 4) LN over sequence: stats then normalize+transpose -> R1 (xt [B,D,S])
    k4a_stats<<<dim3(D_/256, B_), 256, 0, stream>>>(R0, meanc, invc);
    k4b_ntrans<<<dim3(S_/64, D_/64, B_), 256, 0, stream>>>(R0, meanc, invc, a_c, b_c, R1);
    // 5) channel QKV: R1 @ Wc[n] + bc[n] -> qc:R2, kc:R3, vc:R0
    float* qkvc[3] = {R2, R3, R0};
    for (int nn = 0; nn < 3; nn++) {
        mm_bias<<<dim3(S_/128, (B_*D_)/128, 1), 256, 0, stream>>>(
            R1, Wc + (size_t)nn*S_*S_, bc + (size_t)nn*S_, qkvc[nn],
            B_*D_, S_, S_, 0, 0, 0);
    }
    // 6) channel attention -> R1 (xcatt [B,D,S])
    k6_attn_c<<<dim3(D_/256, HC_, B_), 256, 0, stream>>>(R2, R3, R0, R1);
    // 7) final projection: R1 @ Wc[3] + bc[3] -> R0 (y [B,D,S])
    mm_bias<<<dim3(S_/128, (B_*D_)/128, 1), 256, 0, stream>>>(
        R1, Wc + (size_t)3*S_*S_, bc + (size_t)3*S_, R0,
        B_*D_, S_, S_, 0, 0, 0);
    // 8) transpose y -> out [B,S,D]
    k8_trans<<<dim3(S_/64, D_/64, B_), 256, 0, stream>>>(R0, out);
}